// Round 8
// baseline (8632.910 us; speedup 1.0000x reference)
//
#include <hip/hip_runtime.h>
#include <math.h>

#define TPB 256

__device__ __forceinline__ float gelu_f(float x) {
  return 0.5f * x * (1.0f + erff(x * 0.70710678118654752f));
}

// ---------------- head conv 3x3, reflect pad, 3->64, writes R and Y ----------------
__global__ void head_conv_kernel(const float* __restrict__ x, const float* __restrict__ w,
                                 const float* __restrict__ bias, float* __restrict__ R,
                                 float* __restrict__ Y) {
  int idx = blockIdx.x * TPB + threadIdx.x;           // 4*64*192*192
  int wc = idx % 192; int t = idx / 192; int h = t % 192; t /= 192; int oc = t % 64; int b = t / 64;
  float acc = bias[oc];
  #pragma unroll
  for (int kh = 0; kh < 3; kh++) {
    int hh = h + kh - 1; hh = (hh < 0) ? -hh : (hh > 191 ? 382 - hh : hh);
    #pragma unroll
    for (int kw = 0; kw < 3; kw++) {
      int ww = wc + kw - 1; ww = (ww < 0) ? -ww : (ww > 191 ? 382 - ww : ww);
      #pragma unroll
      for (int ic = 0; ic < 3; ic++)
        acc += x[((b * 3 + ic) * 192 + hh) * 192 + ww] * w[((oc * 3 + ic) * 3 + kh) * 3 + kw];
    }
  }
  R[idx] = acc; Y[idx] = acc;
}

// ---------------- instance norm: one block per (b,c) ----------------
__global__ void instnorm_kernel(const float* __restrict__ Y, float* __restrict__ Z) {
  int bc = blockIdx.x;
  const float* in = Y + (size_t)bc * 36864;
  float* out = Z + (size_t)bc * 36864;
  double s = 0.0, s2 = 0.0;
  for (int i = threadIdx.x; i < 36864; i += TPB) { float v = in[i]; s += v; s2 += (double)v * v; }
  __shared__ double sh0[TPB]; __shared__ double sh1[TPB];
  sh0[threadIdx.x] = s; sh1[threadIdx.x] = s2; __syncthreads();
  for (int off = 128; off > 0; off >>= 1) {
    if (threadIdx.x < off) { sh0[threadIdx.x] += sh0[threadIdx.x + off]; sh1[threadIdx.x] += sh1[threadIdx.x + off]; }
    __syncthreads();
  }
  __shared__ float mb, rb;
  if (threadIdx.x == 0) {
    double m = sh0[0] / 36864.0;
    double var = sh1[0] / 36864.0 - m * m;
    mb = (float)m; rb = (float)(1.0 / sqrt(var + 1e-5));
  }
  __syncthreads();
  float m = mb, r = rb;
  for (int i = threadIdx.x; i < 36864; i += TPB) out[i] = (in[i] - m) * r;
}

// ---------------- fused mix + 1-level DWT ----------------
__global__ void mixdwt1_kernel(float* __restrict__ Z, float* __restrict__ D, int g) {
  int idx = blockIdx.x * TPB + threadIdx.x;           // 4*16*96*96 = 589824
  int w2 = idx % 96; int t = idx / 96; int h2 = t % 96; t /= 96; int c = t % 16; int b = t / 16;
  float* zb = Z + (size_t)b * 2359296 + (size_t)(g * 16 + c) * 36864;
  const float* pb = zb - 589824;
  int r0 = (2 * h2) * 192 + 2 * w2;
  float2 top = *(float2*)&zb[r0]; float2 bot = *(float2*)&zb[r0 + 192];
  float2 pt = *(const float2*)&pb[r0]; float2 pbm = *(const float2*)&pb[r0 + 192];
  float a  = 0.5f * (top.x + pt.x);
  float cc = 0.5f * (top.y + pt.y);
  float bb = 0.5f * (bot.x + pbm.x);
  float dd = 0.5f * (bot.y + pbm.y);
  *(float2*)&zb[r0] = make_float2(a, cc);
  *(float2*)&zb[r0 + 192] = make_float2(bb, dd);
  size_t ob = ((size_t)b * 64 + c) * 9216 + (size_t)h2 * 96 + w2;
  D[ob]             = 0.5f * ( a + bb + cc + dd);
  D[ob + 16 * 9216] = 0.5f * (-a - bb + cc + dd);
  D[ob + 32 * 9216] = 0.5f * (-a + bb - cc + dd);
  D[ob + 48 * 9216] = 0.5f * ( a - bb - cc + dd);
}

// ---------------- fused mix + 2-level DWT ----------------
__global__ void mixdwt2_kernel(float* __restrict__ Z, float* __restrict__ D, int g) {
  int idx = blockIdx.x * TPB + threadIdx.x;           // 4*16*48*48 = 147456
  int w4 = idx % 48; int t = idx / 48; int h4 = t % 48; t /= 48; int c = t % 16; int b = t / 16;
  float* zb = Z + (size_t)b * 2359296 + (size_t)(g * 16 + c) * 36864;
  const float* pb = zb - 589824;
  float m[4][4];
  #pragma unroll
  for (int r = 0; r < 4; r++) {
    int off = (4 * h4 + r) * 192 + 4 * w4;
    float4 v = *(float4*)&zb[off];
    float4 pv = *(const float4*)&pb[off];
    m[r][0] = 0.5f * (v.x + pv.x); m[r][1] = 0.5f * (v.y + pv.y);
    m[r][2] = 0.5f * (v.z + pv.z); m[r][3] = 0.5f * (v.w + pv.w);
    *(float4*)&zb[off] = make_float4(m[r][0], m[r][1], m[r][2], m[r][3]);
  }
  float A[4][2][2];
  #pragma unroll
  for (int p = 0; p < 2; p++)
    #pragma unroll
    for (int q = 0; q < 2; q++) {
      float a  = m[2 * p][2 * q];
      float bb = m[2 * p + 1][2 * q];
      float cc = m[2 * p][2 * q + 1];
      float dd = m[2 * p + 1][2 * q + 1];
      A[0][p][q] = 0.5f * ( a + bb + cc + dd);
      A[1][p][q] = 0.5f * (-a - bb + cc + dd);
      A[2][p][q] = 0.5f * (-a + bb - cc + dd);
      A[3][p][q] = 0.5f * ( a - bb - cc + dd);
    }
  size_t ob = (size_t)b * 589824 + (size_t)c * 2304 + (size_t)h4 * 48 + w4;
  #pragma unroll
  for (int s1 = 0; s1 < 4; s1++) {
    float a = A[s1][0][0], bb = A[s1][1][0], cc = A[s1][0][1], dd = A[s1][1][1];
    size_t o = ob + (size_t)(s1 * 16) * 2304;
    D[o]                = 0.5f * ( a + bb + cc + dd);
    D[o +  64 * 2304]   = 0.5f * (-a - bb + cc + dd);
    D[o + 128 * 2304]   = 0.5f * (-a + bb - cc + dd);
    D[o + 192 * 2304]   = 0.5f * ( a - bb - cc + dd);
  }
}

// ---------------- IWT (1-level): add into strided dest ----------------
__global__ void iwt_kernel(const float* __restrict__ in, float* __restrict__ out,
                           int C, int H, int W, long long obStride, int og0, int addFlag) {
  int idx = blockIdx.x * TPB + threadIdx.x;
  int w = idx % W; int t = idx / W; int h = t % H; t /= H; int c = t % C; int b = t / C;
  size_t HW = (size_t)H * W; size_t CHW = (size_t)C * HW;
  size_t base = (size_t)b * 4 * CHW + (size_t)c * HW + (size_t)h * W + w;
  float x1 = in[base], x2 = in[base + CHW], x3 = in[base + 2 * CHW], x4 = in[base + 3 * CHW];
  float p00 = 0.5f * (x1 - x2 - x3 + x4);
  float p10 = 0.5f * (x1 - x2 + x3 - x4);
  float p01 = 0.5f * (x1 + x2 - x3 - x4);
  float p11 = 0.5f * (x1 + x2 + x3 + x4);
  int W2 = 2 * W;
  float* op = out + (size_t)b * obStride + (size_t)(og0 + c) * (4 * HW) + (size_t)(2 * h) * W2 + 2 * w;
  if (addFlag) { op[0] += p00; op[1] += p01; op[W2] += p10; op[W2 + 1] += p11; }
  else         { op[0] = p00;  op[1] = p01;  op[W2] = p10;  op[W2 + 1] = p11; }
}

// ---------------- fused 2-level IWT + residual add into Z[g] ----------------
__global__ void iwt2add_kernel(const float* __restrict__ X, float* __restrict__ Z, int g) {
  int idx = blockIdx.x * TPB + threadIdx.x;           // 147456
  int w = idx % 48; int t = idx / 48; int h = t % 48; t /= 48; int c = t % 16; int b = t / 16;
  const float* xb = X + (size_t)b * 589824 + (size_t)h * 48 + w;
  float xv[4][4];
  #pragma unroll
  for (int s2 = 0; s2 < 4; s2++)
    #pragma unroll
    for (int s1 = 0; s1 < 4; s1++)
      xv[s2][s1] = xb[(size_t)(s2 * 64 + s1 * 16 + c) * 2304];
  float Yv[4][2][2];
  #pragma unroll
  for (int s1 = 0; s1 < 4; s1++) {
    float X0 = xv[0][s1], X1 = xv[1][s1], X2 = xv[2][s1], X3 = xv[3][s1];
    Yv[s1][0][0] = 0.5f * (X0 - X1 - X2 + X3);
    Yv[s1][0][1] = 0.5f * (X0 + X1 - X2 - X3);
    Yv[s1][1][0] = 0.5f * (X0 - X1 + X2 - X3);
    Yv[s1][1][1] = 0.5f * (X0 + X1 + X2 + X3);
  }
  float* zb = Z + (size_t)b * 2359296 + (size_t)(g * 16 + c) * 36864;
  #pragma unroll
  for (int p = 0; p < 2; p++)
    #pragma unroll
    for (int i = 0; i < 2; i++) {
      float Y0q0 = Yv[0][p][0], Y1q0 = Yv[1][p][0], Y2q0 = Yv[2][p][0], Y3q0 = Yv[3][p][0];
      float Y0q1 = Yv[0][p][1], Y1q1 = Yv[1][p][1], Y2q1 = Yv[2][p][1], Y3q1 = Yv[3][p][1];
      float si = (i == 0) ? -1.f : 1.f;
      float zq0j0 = 0.5f * (Y0q0 - Y1q0 + si * Y2q0 - si * Y3q0);
      float zq0j1 = 0.5f * (Y0q0 + Y1q0 + si * Y2q0 + si * Y3q0);
      float zq1j0 = 0.5f * (Y0q1 - Y1q1 + si * Y2q1 - si * Y3q1);
      float zq1j1 = 0.5f * (Y0q1 + Y1q1 + si * Y2q1 + si * Y3q1);
      int off = (4 * h + 2 * p + i) * 192 + 4 * w;
      float4 cur = *(float4*)&zb[off];
      cur.x += zq0j0; cur.y += zq0j1; cur.z += zq1j0; cur.w += zq1j1;
      *(float4*)&zb[off] = cur;
    }
}

// ---------------- qkv einsum v3: 16 outputs x 3 pixels per thread ----------------
// 768-pixel tiles (divides 36864/9216/2304). FMA:SMEM = 12:1.
__global__ __launch_bounds__(256, 4) void qkv_kernel(const float* __restrict__ in, const float* __restrict__ w,
                           float* __restrict__ out, int C, int HW, long long ibStride, int ig0) {
  int PT = HW / 768;
  int OT3 = (3 * C) >> 4;
  int blk = blockIdx.x;
  int pt = blk % PT; int t = blk / PT; int ot = t % OT3; int b = t / OT3;
  int p = pt * 768 + threadIdx.x;                      // p, p+256, p+512
  const float* ip = in + (size_t)b * ibStride + (size_t)ig0 * HW + p;
  int o0 = ot * 16;
  float acc[3][16];
  #pragma unroll
  for (int u = 0; u < 3; u++)
    #pragma unroll
    for (int i = 0; i < 16; i++) acc[u][i] = 0.f;
  for (int c = 0; c < C; c += 4) {
    float v[3][4];
    #pragma unroll
    for (int j = 0; j < 4; j++) {
      const float* cp = ip + (size_t)(c + j) * HW;
      v[0][j] = cp[0]; v[1][j] = cp[256]; v[2][j] = cp[512];
    }
    #pragma unroll
    for (int i = 0; i < 16; i++) {
      const float4 wv = *(const float4*)(w + (size_t)(o0 + i) * C + c);   // uniform -> s_load_dwordx4
      #pragma unroll
      for (int u = 0; u < 3; u++)
        acc[u][i] += v[u][0] * wv.x + v[u][1] * wv.y + v[u][2] * wv.z + v[u][3] * wv.w;
    }
  }
  float* op = out + ((size_t)b * 3 * C + o0) * HW + p;
  #pragma unroll
  for (int i = 0; i < 16; i++) {
    float* r = op + (size_t)i * HW;
    r[0] = acc[0][i]; r[256] = acc[1][i]; r[512] = acc[2][i];
  }
}

// ---------------- halo attention v2: lane<->query row, wave<->j/d slice ----------------
template <int D>
__global__ __launch_bounds__(256) void attn_kernel(
    const float* __restrict__ qkv, const float* __restrict__ rh, const float* __restrict__ rw,
    float* __restrict__ out, int nh, int nw, int H, int W, long long obStride, int og0, int addFlag) {
  constexpr int DC = (D < 32) ? D : 32;
  constexpr int NCH = D / DC;
  constexpr int HALF = D / 2;
  constexpr int SKS = DC + 4;
  constexpr int CPW = DC / 4;
  __shared__ __align__(16) float sK[100 * SKS];
  __shared__ float sS[64 * 101];
  int blk = blockIdx.x; int nb = nh * nw;
  int b = blk / nb; int r = blk % nb; int by = r / nw; int bx = r % nw;
  size_t HWs = (size_t)H * W;
  const float* qb = qkv + (size_t)b * 3 * D * HWs;
  float qs = rsqrtf((float)D);
  int tid = threadIdx.x;
  int w = tid >> 6, lane = tid & 63;
  int qy = by * 8 + (lane >> 3), qx = bx * 8 + (lane & 7);
  const float* qpix = qb + (size_t)qy * W + qx;
  float acc[25];
  #pragma unroll
  for (int jj = 0; jj < 25; jj++) acc[jj] = 0.f;
  for (int ch = 0; ch < NCH; ch++) {
    int dc0 = ch * DC;
    if (ch) __syncthreads();
    for (int idx = tid; idx < 100 * DC; idx += TPB) {
      int j = idx % 100, c = idx / 100;
      int pr = j / 10, pc = j % 10;
      int hy = by * 8 - 1 + pr, hx = bx * 8 - 1 + pc;
      float v = 0.f;
      if (hy >= 0 && hy < H && hx >= 0 && hx < W)
        v = qb[(size_t)(D + dc0 + c) * HWs + (size_t)hy * W + hx];
      int cg = dc0 + c;
      v += (cg < HALF) ? rh[pr * HALF + cg] : rw[pc * HALF + (cg - HALF)];
      sK[j * SKS + c] = v;
    }
    __syncthreads();
    float qr[DC];
    #pragma unroll
    for (int c = 0; c < DC; c++) qr[c] = qpix[(size_t)(dc0 + c) * HWs] * qs;
    #pragma unroll
    for (int jj = 0; jj < 25; jj++) {
      int j = w * 25 + jj;
      const float4* k4 = (const float4*)&sK[j * SKS];
      float a = 0.f;
      #pragma unroll
      for (int c4 = 0; c4 < DC / 4; c4++) {
        float4 kv = k4[c4];
        a += qr[4 * c4] * kv.x + qr[4 * c4 + 1] * kv.y + qr[4 * c4 + 2] * kv.z + qr[4 * c4 + 3] * kv.w;
      }
      acc[jj] += a;
    }
  }
  #pragma unroll
  for (int jj = 0; jj < 25; jj++) sS[lane * 101 + w * 25 + jj] = acc[jj];
  __syncthreads();
  if (tid < 64) {
    float mx = -3.4e38f;
    for (int j = 0; j < 100; j++) mx = fmaxf(mx, sS[tid * 101 + j]);
    float s = 0.f;
    for (int j = 0; j < 100; j++) { float e = expf(sS[tid * 101 + j] - mx); sS[tid * 101 + j] = e; s += e; }
    float inv = 1.f / s;
    for (int j = 0; j < 100; j++) sS[tid * 101 + j] *= inv;
  }
  for (int ch = 0; ch < NCH; ch++) {
    int dc0 = ch * DC;
    __syncthreads();
    for (int idx = tid; idx < 100 * DC; idx += TPB) {
      int j = idx % 100, c = idx / 100;
      int pr = j / 10, pc = j % 10;
      int hy = by * 8 - 1 + pr, hx = bx * 8 - 1 + pc;
      float v = 0.f;
      if (hy >= 0 && hy < H && hx >= 0 && hx < W)
        v = qb[(size_t)(2 * D + dc0 + c) * HWs + (size_t)hy * W + hx];
      sK[j * SKS + c] = v;
    }
    __syncthreads();
    float oacc[CPW];
    #pragma unroll
    for (int cc = 0; cc < CPW; cc++) oacc[cc] = 0.f;
    const float* srow = &sS[lane * 101];
    for (int j = 0; j < 100; j++) {
      float p = srow[j];
      const float4* v4 = (const float4*)&sK[j * SKS + w * CPW];
      #pragma unroll
      for (int c4 = 0; c4 < CPW / 4; c4++) {
        float4 vv = v4[c4];
        oacc[4 * c4]     += p * vv.x;
        oacc[4 * c4 + 1] += p * vv.y;
        oacc[4 * c4 + 2] += p * vv.z;
        oacc[4 * c4 + 3] += p * vv.w;
      }
    }
    size_t o = (size_t)b * obStride + (size_t)(og0 + dc0 + w * CPW) * HWs + (size_t)qy * W + qx;
    #pragma unroll
    for (int cc = 0; cc < CPW; cc++) {
      if (addFlag) out[o + (size_t)cc * HWs] += oacc[cc];
      else         out[o + (size_t)cc * HWs]  = oacc[cc];
    }
  }
}

// ---------------- ff conv 3x3 zero-pad 64->64 + bias + residual (in-place Y) ----------------
__global__ __launch_bounds__(256, 4) void ffconv_kernel(const float* __restrict__ Z,
    const float* __restrict__ w, const float* __restrict__ bias, float* __restrict__ Y) {
  __shared__ float sX[324 * 17];
  int blk = blockIdx.x; int b = blk / 144; int tile = blk % 144;
  int ty = (tile / 12) * 16, tx = (tile % 12) * 16;
  int tid = threadIdx.x;
  int px = tid & 15, py = tid >> 4;
  float acc[64];
  #pragma unroll
  for (int oc = 0; oc < 64; oc++) acc[oc] = 0.f;
  for (int ic0 = 0; ic0 < 64; ic0 += 16) {
    __syncthreads();
    for (int idx = tid; idx < 324 * 16; idx += TPB) {
      int cc = idx / 324; int pix = idx % 324;
      int rr = pix / 18, c = pix % 18;
      int hh = ty + rr - 1, ww = tx + c - 1;
      float v = 0.f;
      if (hh >= 0 && hh < 192 && ww >= 0 && ww < 192)
        v = Z[((size_t)(b * 64 + ic0 + cc) * 192 + hh) * 192 + ww];
      sX[pix * 17 + cc] = v;
    }
    __syncthreads();
    for (int ic = 0; ic < 16; ic++) {
      float xv[9];
      #pragma unroll
      for (int kh = 0; kh < 3; kh++)
        #pragma unroll
        for (int kw = 0; kw < 3; kw++)
          xv[kh * 3 + kw] = sX[((py + kh) * 18 + (px + kw)) * 17 + ic];
      const float* wp = w + (size_t)(ic0 + ic) * 9;
      #pragma unroll
      for (int oc = 0; oc < 64; oc++) {
        float a = acc[oc];
        const float* wr = wp + (size_t)oc * 576;
        #pragma unroll
        for (int k = 0; k < 9; k++) a += xv[k] * wr[k];
        acc[oc] = a;
      }
    }
  }
  size_t base = (size_t)b * 2359296 + (size_t)(ty + py) * 192 + (tx + px);
  #pragma unroll
  for (int oc = 0; oc < 64; oc++) {
    size_t o = base + (size_t)oc * 36864;
    Y[o] = acc[oc] + bias[oc] + Y[o];
  }
}

// ---------------- t1: (Y+R) conv1x1(64->256) + pixel_shuffle(2) + gelu -> U1 ----------------
__global__ __launch_bounds__(256, 4) void t1_kernel(const float* __restrict__ Y, const float* __restrict__ R,
    const float* __restrict__ w, const float* __restrict__ bias, float* __restrict__ U1) {
  int blk = blockIdx.x; int b = blk / 144; int p0 = (blk % 144) * 256;
  int tid = threadIdx.x;
  int p = p0 + tid;
  float yv[64];
  const float* yp = Y + (size_t)b * 2359296 + p;
  const float* rp = R + (size_t)b * 2359296 + p;
  #pragma unroll
  for (int c = 0; c < 64; c++) yv[c] = yp[(size_t)c * 36864] + rp[(size_t)c * 36864];
  int h = p / 192, wc = p % 192;
  float* ub = U1 + (size_t)b * 9437184 + (size_t)(2 * h) * 384 + 2 * wc;
  for (int c2 = 0; c2 < 64; c2++) {
    float a0 = bias[c2 * 4 + 0], a1 = bias[c2 * 4 + 1], a2 = bias[c2 * 4 + 2], a3 = bias[c2 * 4 + 3];
    const float* w0 = w + (size_t)(c2 * 4) * 64;
    const float* w1 = w0 + 64; const float* w2p = w0 + 128; const float* w3p = w0 + 192;
    #pragma unroll
    for (int c = 0; c < 64; c++) {
      float y = yv[c];
      a0 += y * w0[c]; a1 += y * w1[c]; a2 += y * w2p[c]; a3 += y * w3p[c];
    }
    float* up = ub + (size_t)c2 * 147456;
    up[0] = gelu_f(a0); up[1] = gelu_f(a1); up[384] = gelu_f(a2); up[385] = gelu_f(a3);
  }
}

// ---------------- fused tail: t2 conv1x1+ps+gelu -> t3 conv3x3(reflect) -> clip ----------------
// t2 K-loop split into two ic-halves: only u1v[32] live at a time. Half 0 writes RAW
// partial av into the thread's own sU2p slots (same-thread readback, no barrier);
// half 1 reloads u1v (L1/L2-hot), accumulates, gelus, rewrites. Live set ~70 regs.
__global__ __launch_bounds__(256, 4) void tail_kernel(const float* __restrict__ U1,
    const float* __restrict__ w2, const float* __restrict__ b2,
    const float* __restrict__ w3, float* __restrict__ out) {
  __shared__ float2 sU2p[4][1024];                    // plane q: ic pair (2q,2q+1), pix 32x32
  int blk = blockIdx.x;
  int b = blk / 784; int tile = blk % 784;
  int tr = tile / 28, tc = tile % 28;
  int r0 = tr * 28, c0 = tc * 28;
  int s0 = (r0 >> 1) - 1, t0 = (c0 >> 1) - 1;
  int tid = threadIdx.x;
  int ls = tid >> 4, lt = tid & 15;
  int gs = min(max(s0 + ls, 0), 383);
  int gt = min(max(t0 + lt, 0), 383);
  const float* ub = U1 + (size_t)b * 9437184 + (size_t)gs * 384 + gt;
  int orow[4], ocol[4]; bool val[4];
  #pragma unroll
  for (int k = 0; k < 4; k++) {
    int p = tid + k * 256;
    int y = p / 28, x = p % 28;
    orow[k] = r0 + y; ocol[k] = c0 + x;
    val[k] = (p < 784) && (orow[k] < 768) && (ocol[k] < 768);
  }
  float acc0[4], acc1[4], acc2[4];
  #pragma unroll
  for (int k = 0; k < 4; k++) { acc0[k] = 0.f; acc1[k] = 0.f; acc2[k] = 0.f; }
  int urow = 2 * ls, ucol = 2 * lt;
  int mypix[4];
  #pragma unroll
  for (int par = 0; par < 4; par++) mypix[par] = (urow + (par >> 1)) * 32 + (ucol + (par & 1));
  for (int ch = 0; ch < 8; ch++) {
    if (ch) __syncthreads();
    // ---- t2 half 0: ic 0..31, store raw partials ----
    {
      float u1v[32];
      #pragma unroll
      for (int c = 0; c < 32; c++) u1v[c] = ub[(size_t)c * 147456];
      #pragma unroll
      for (int rg = 0; rg < 4; rg++) {
        float av[8];
        #pragma unroll
        for (int r = 0; r < 8; r++) av[r] = b2[ch * 32 + rg * 8 + r];
        #pragma unroll
        for (int c4 = 0; c4 < 8; c4++) {
          float ux = u1v[4 * c4], uy = u1v[4 * c4 + 1], uz = u1v[4 * c4 + 2], uw = u1v[4 * c4 + 3];
          #pragma unroll
          for (int r = 0; r < 8; r++) {
            const float4 wv = *(const float4*)(w2 + (size_t)(ch * 32 + rg * 8 + r) * 64 + c4 * 4);
            av[r] += ux * wv.x + uy * wv.y + uz * wv.z + uw * wv.w;
          }
        }
        #pragma unroll
        for (int par = 0; par < 4; par++)
          sU2p[rg][mypix[par]] = make_float2(av[par], av[4 + par]);   // raw partial
      }
    }
    // ---- t2 half 1: ic 32..63, accumulate + gelu ----
    {
      float u1v[32];
      #pragma unroll
      for (int c = 0; c < 32; c++) u1v[c] = ub[(size_t)(32 + c) * 147456];
      #pragma unroll
      for (int rg = 0; rg < 4; rg++) {
        float av[8];
        #pragma unroll
        for (int par = 0; par < 4; par++) {
          float2 pv = sU2p[rg][mypix[par]];            // own slot, same thread
          av[par] = pv.x; av[4 + par] = pv.y;
        }
        #pragma unroll
        for (int c4 = 0; c4 < 8; c4++) {
          float ux = u1v[4 * c4], uy = u1v[4 * c4 + 1], uz = u1v[4 * c4 + 2], uw = u1v[4 * c4 + 3];
          #pragma unroll
          for (int r = 0; r < 8; r++) {
            const float4 wv = *(const float4*)(w2 + (size_t)(ch * 32 + rg * 8 + r) * 64 + 32 + c4 * 4);
            av[r] += ux * wv.x + uy * wv.y + uz * wv.z + uw * wv.w;
          }
        }
        #pragma unroll
        for (int par = 0; par < 4; par++)
          sU2p[rg][mypix[par]] = make_float2(gelu_f(av[par]), gelu_f(av[4 + par]));
      }
    }
    __syncthreads();
    // ---- t3 partial accumulation ----
    #pragma unroll
    for (int k = 0; k < 4; k++) {
      if (!val[k]) continue;
      float s0a = acc0[k], s1a = acc1[k], s2a = acc2[k];
      #pragma unroll
      for (int kh = 0; kh < 3; kh++) {
        int pp = orow[k] - 1 + kh; int mp = pp < 0 ? -pp : (pp > 767 ? 1534 - pp : pp);
        int lr = mp - r0 + 2;
        #pragma unroll
        for (int kw = 0; kw < 3; kw++) {
          int qq = ocol[k] - 1 + kw; int mq = qq < 0 ? -qq : (qq > 767 ? 1534 - qq : qq);
          int lc = mq - c0 + 2;
          int pix = lr * 32 + lc;
          float2 u01 = sU2p[0][pix], u23 = sU2p[1][pix], u45 = sU2p[2][pix], u67 = sU2p[3][pix];
          const float* w3p = w3 + (size_t)(ch * 8) * 9 + kh * 3 + kw;   // + oc*576 + g*9
          s0a += u01.x * w3p[0]    + u01.y * w3p[9]    + u23.x * w3p[18]   + u23.y * w3p[27]
               + u45.x * w3p[36]   + u45.y * w3p[45]   + u67.x * w3p[54]   + u67.y * w3p[63];
          s1a += u01.x * w3p[576]  + u01.y * w3p[585]  + u23.x * w3p[594]  + u23.y * w3p[603]
               + u45.x * w3p[612]  + u45.y * w3p[621]  + u67.x * w3p[630]  + u67.y * w3p[639];
          s2a += u01.x * w3p[1152] + u01.y * w3p[1161] + u23.x * w3p[1170] + u23.y * w3p[1179]
               + u45.x * w3p[1188] + u45.y * w3p[1197] + u67.x * w3p[1206] + u67.y * w3p[1215];
        }
      }
      acc0[k] = s0a; acc1[k] = s1a; acc2[k] = s2a;
    }
  }
  #pragma unroll
  for (int k = 0; k < 4; k++) {
    if (!val[k]) continue;
    size_t o = ((size_t)b * 3 * 768 + orow[k]) * 768 + ocol[k];
    out[o] = fminf(fmaxf(acc0[k], 0.f), 1.f);
    out[o + 589824] = fminf(fmaxf(acc1[k], 0.f), 1.f);
    out[o + 1179648] = fminf(fmaxf(acc2[k], 0.f), 1.f);
  }
}

extern "C" void kernel_launch(void* const* d_in, const int* in_sizes, int n_in,
                              void* d_out, int out_size, void* d_ws, size_t ws_size,
                              hipStream_t stream) {
  const float* x      = (const float*)d_in[0];
  const float* head_w = (const float*)d_in[1];
  const float* head_b = (const float*)d_in[2];
  const float* a_qkv[4] = {(const float*)d_in[3], (const float*)d_in[6], (const float*)d_in[9],  (const float*)d_in[12]};
  const float* a_rh[4]  = {(const float*)d_in[4], (const float*)d_in[7], (const float*)d_in[10], (const float*)d_in[13]};
  const float* a_rw[4]  = {(const float*)d_in[5], (const float*)d_in[8], (const float*)d_in[11], (const float*)d_in[14]};
  const float* ff_w = (const float*)d_in[15];
  const float* ff_b = (const float*)d_in[16];
  const float* t1_w = (const float*)d_in[17];
  const float* t1_b = (const float*)d_in[18];
  const float* t2_w = (const float*)d_in[19];
  const float* t2_b = (const float*)d_in[20];
  const float* t3_w = (const float*)d_in[21];
  float* outp = (float*)d_out;
  float* wsf = (float*)d_ws;

  const size_t F = 9437184;                 // 4*64*192*192
  float* R   = wsf;
  float* Y   = wsf + F;
  float* Z   = wsf + 2 * F;
  float* QKV = wsf + 3 * F;                 // 7,077,888 floats
  float* AO  = QKV + 7077888;               // 2,359,296
  float* D1  = AO + 2359296;                // 2,359,296
  float* D2  = D1 + 2359296;                // 2,359,296
  float* U1  = Z;                           // tail reuses CFTM scratch

  head_conv_kernel<<<36864, TPB, 0, stream>>>(x, head_w, head_b, R, Y);

  for (int bi = 0; bi < 4; bi++) {
    instnorm_kernel<<<256, TPB, 0, stream>>>(Y, Z);
    // branch 1 (d=16, 192x192)
    qkv_kernel<<<576, TPB, 0, stream>>>(Z, a_qkv[0] + bi * 768, QKV, 16, 36864, 2359296LL, 0);
    attn_kernel<16><<<2304, TPB, 0, stream>>>(QKV, a_rh[0] + bi * 80, a_rw[0] + bi * 80, Z,
                                              24, 24, 192, 192, 2359296LL, 0, 1);
    // branch 2 (d=64, 96x96)
    mixdwt1_kernel<<<2304, TPB, 0, stream>>>(Z, D1, 1);
    qkv_kernel<<<576, TPB, 0, stream>>>(D1, a_qkv[1] + bi * 12288, QKV, 64, 9216, 589824LL, 0);
    attn_kernel<64><<<576, TPB, 0, stream>>>(QKV, a_rh[1] + bi * 320, a_rw[1] + bi * 320, AO,
                                             12, 12, 96, 96, 589824LL, 0, 0);
    iwt_kernel<<<2304, TPB, 0, stream>>>(AO, Z, 16, 96, 96, 2359296LL, 16, 1);
    // branch 3 (d=256, 48x48)
    mixdwt2_kernel<<<576, TPB, 0, stream>>>(Z, D2, 2);
    qkv_kernel<<<576, TPB, 0, stream>>>(D2, a_qkv[2] + bi * 196608, QKV, 256, 2304, 589824LL, 0);
    attn_kernel<256><<<144, TPB, 0, stream>>>(QKV, a_rh[2] + bi * 1280, a_rw[2] + bi * 1280, AO,
                                              6, 6, 48, 48, 589824LL, 0, 0);
    iwt2add_kernel<<<576, TPB, 0, stream>>>(AO, Z, 2);
    // branch 4 (d=256, 48x48)
    mixdwt2_kernel<<<576, TPB, 0, stream>>>(Z, D2, 3);
    qkv_kernel<<<576, TPB, 0, stream>>>(D2, a_qkv[3] + bi * 196608, QKV, 256, 2304, 589824LL, 0);
    attn_kernel<256><<<144, TPB, 0, stream>>>(QKV, a_rh[3] + bi * 1280, a_rw[3] + bi * 1280, AO,
                                              6, 6, 48, 48, 589824LL, 0, 0);
    iwt2add_kernel<<<576, TPB, 0, stream>>>(AO, Z, 3);
    // ff conv + residual
    ffconv_kernel<<<576, TPB, 0, stream>>>(Z, ff_w + bi * 36864, ff_b + bi * 64, Y);
  }

  t1_kernel<<<576, TPB, 0, stream>>>(Y, R, t1_w, t1_b, U1);
  tail_kernel<<<3136, TPB, 0, stream>>>(U1, t2_w, t2_b, t3_w, outp);
}

// Round 9
// 6583.645 us; speedup vs baseline: 1.3113x; 1.3113x over previous
//
#include <hip/hip_runtime.h>
#include <math.h>

#define TPB 256

__device__ __forceinline__ float gelu_f(float x) {
  return 0.5f * x * (1.0f + erff(x * 0.70710678118654752f));
}

// ---------------- head conv 3x3, reflect pad, 3->64, writes R and Y ----------------
__global__ void head_conv_kernel(const float* __restrict__ x, const float* __restrict__ w,
                                 const float* __restrict__ bias, float* __restrict__ R,
                                 float* __restrict__ Y) {
  int idx = blockIdx.x * TPB + threadIdx.x;           // 4*64*192*192
  int wc = idx % 192; int t = idx / 192; int h = t % 192; t /= 192; int oc = t % 64; int b = t / 64;
  float acc = bias[oc];
  #pragma unroll
  for (int kh = 0; kh < 3; kh++) {
    int hh = h + kh - 1; hh = (hh < 0) ? -hh : (hh > 191 ? 382 - hh : hh);
    #pragma unroll
    for (int kw = 0; kw < 3; kw++) {
      int ww = wc + kw - 1; ww = (ww < 0) ? -ww : (ww > 191 ? 382 - ww : ww);
      #pragma unroll
      for (int ic = 0; ic < 3; ic++)
        acc += x[((b * 3 + ic) * 192 + hh) * 192 + ww] * w[((oc * 3 + ic) * 3 + kh) * 3 + kw];
    }
  }
  R[idx] = acc; Y[idx] = acc;
}

// ---------------- instance norm: one block per (b,c) ----------------
__global__ void instnorm_kernel(const float* __restrict__ Y, float* __restrict__ Z) {
  int bc = blockIdx.x;
  const float* in = Y + (size_t)bc * 36864;
  float* out = Z + (size_t)bc * 36864;
  double s = 0.0, s2 = 0.0;
  for (int i = threadIdx.x; i < 36864; i += TPB) { float v = in[i]; s += v; s2 += (double)v * v; }
  __shared__ double sh0[TPB]; __shared__ double sh1[TPB];
  sh0[threadIdx.x] = s; sh1[threadIdx.x] = s2; __syncthreads();
  for (int off = 128; off > 0; off >>= 1) {
    if (threadIdx.x < off) { sh0[threadIdx.x] += sh0[threadIdx.x + off]; sh1[threadIdx.x] += sh1[threadIdx.x + off]; }
    __syncthreads();
  }
  __shared__ float mb, rb;
  if (threadIdx.x == 0) {
    double m = sh0[0] / 36864.0;
    double var = sh1[0] / 36864.0 - m * m;
    mb = (float)m; rb = (float)(1.0 / sqrt(var + 1e-5));
  }
  __syncthreads();
  float m = mb, r = rb;
  for (int i = threadIdx.x; i < 36864; i += TPB) out[i] = (in[i] - m) * r;
}

// ---------------- fused mix + 1-level DWT ----------------
__global__ void mixdwt1_kernel(float* __restrict__ Z, float* __restrict__ D, int g) {
  int idx = blockIdx.x * TPB + threadIdx.x;           // 4*16*96*96 = 589824
  int w2 = idx % 96; int t = idx / 96; int h2 = t % 96; t /= 96; int c = t % 16; int b = t / 16;
  float* zb = Z + (size_t)b * 2359296 + (size_t)(g * 16 + c) * 36864;
  const float* pb = zb - 589824;
  int r0 = (2 * h2) * 192 + 2 * w2;
  float2 top = *(float2*)&zb[r0]; float2 bot = *(float2*)&zb[r0 + 192];
  float2 pt = *(const float2*)&pb[r0]; float2 pbm = *(const float2*)&pb[r0 + 192];
  float a  = 0.5f * (top.x + pt.x);
  float cc = 0.5f * (top.y + pt.y);
  float bb = 0.5f * (bot.x + pbm.x);
  float dd = 0.5f * (bot.y + pbm.y);
  *(float2*)&zb[r0] = make_float2(a, cc);
  *(float2*)&zb[r0 + 192] = make_float2(bb, dd);
  size_t ob = ((size_t)b * 64 + c) * 9216 + (size_t)h2 * 96 + w2;
  D[ob]             = 0.5f * ( a + bb + cc + dd);
  D[ob + 16 * 9216] = 0.5f * (-a - bb + cc + dd);
  D[ob + 32 * 9216] = 0.5f * (-a + bb - cc + dd);
  D[ob + 48 * 9216] = 0.5f * ( a - bb - cc + dd);
}

// ---------------- fused mix + 2-level DWT ----------------
__global__ void mixdwt2_kernel(float* __restrict__ Z, float* __restrict__ D, int g) {
  int idx = blockIdx.x * TPB + threadIdx.x;           // 4*16*48*48 = 147456
  int w4 = idx % 48; int t = idx / 48; int h4 = t % 48; t /= 48; int c = t % 16; int b = t / 16;
  float* zb = Z + (size_t)b * 2359296 + (size_t)(g * 16 + c) * 36864;
  const float* pb = zb - 589824;
  float m[4][4];
  #pragma unroll
  for (int r = 0; r < 4; r++) {
    int off = (4 * h4 + r) * 192 + 4 * w4;
    float4 v = *(float4*)&zb[off];
    float4 pv = *(const float4*)&pb[off];
    m[r][0] = 0.5f * (v.x + pv.x); m[r][1] = 0.5f * (v.y + pv.y);
    m[r][2] = 0.5f * (v.z + pv.z); m[r][3] = 0.5f * (v.w + pv.w);
    *(float4*)&zb[off] = make_float4(m[r][0], m[r][1], m[r][2], m[r][3]);
  }
  float A[4][2][2];
  #pragma unroll
  for (int p = 0; p < 2; p++)
    #pragma unroll
    for (int q = 0; q < 2; q++) {
      float a  = m[2 * p][2 * q];
      float bb = m[2 * p + 1][2 * q];
      float cc = m[2 * p][2 * q + 1];
      float dd = m[2 * p + 1][2 * q + 1];
      A[0][p][q] = 0.5f * ( a + bb + cc + dd);
      A[1][p][q] = 0.5f * (-a - bb + cc + dd);
      A[2][p][q] = 0.5f * (-a + bb - cc + dd);
      A[3][p][q] = 0.5f * ( a - bb - cc + dd);
    }
  size_t ob = (size_t)b * 589824 + (size_t)c * 2304 + (size_t)h4 * 48 + w4;
  #pragma unroll
  for (int s1 = 0; s1 < 4; s1++) {
    float a = A[s1][0][0], bb = A[s1][1][0], cc = A[s1][0][1], dd = A[s1][1][1];
    size_t o = ob + (size_t)(s1 * 16) * 2304;
    D[o]                = 0.5f * ( a + bb + cc + dd);
    D[o +  64 * 2304]   = 0.5f * (-a - bb + cc + dd);
    D[o + 128 * 2304]   = 0.5f * (-a + bb - cc + dd);
    D[o + 192 * 2304]   = 0.5f * ( a - bb - cc + dd);
  }
}

// ---------------- IWT (1-level): add into strided dest ----------------
__global__ void iwt_kernel(const float* __restrict__ in, float* __restrict__ out,
                           int C, int H, int W, long long obStride, int og0, int addFlag) {
  int idx = blockIdx.x * TPB + threadIdx.x;
  int w = idx % W; int t = idx / W; int h = t % H; t /= H; int c = t % C; int b = t / C;
  size_t HW = (size_t)H * W; size_t CHW = (size_t)C * HW;
  size_t base = (size_t)b * 4 * CHW + (size_t)c * HW + (size_t)h * W + w;
  float x1 = in[base], x2 = in[base + CHW], x3 = in[base + 2 * CHW], x4 = in[base + 3 * CHW];
  float p00 = 0.5f * (x1 - x2 - x3 + x4);
  float p10 = 0.5f * (x1 - x2 + x3 - x4);
  float p01 = 0.5f * (x1 + x2 - x3 - x4);
  float p11 = 0.5f * (x1 + x2 + x3 + x4);
  int W2 = 2 * W;
  float* op = out + (size_t)b * obStride + (size_t)(og0 + c) * (4 * HW) + (size_t)(2 * h) * W2 + 2 * w;
  if (addFlag) { op[0] += p00; op[1] += p01; op[W2] += p10; op[W2 + 1] += p11; }
  else         { op[0] = p00;  op[1] = p01;  op[W2] = p10;  op[W2 + 1] = p11; }
}

// ---------------- fused 2-level IWT + residual add into Z[g] ----------------
__global__ void iwt2add_kernel(const float* __restrict__ X, float* __restrict__ Z, int g) {
  int idx = blockIdx.x * TPB + threadIdx.x;           // 147456
  int w = idx % 48; int t = idx / 48; int h = t % 48; t /= 48; int c = t % 16; int b = t / 16;
  const float* xb = X + (size_t)b * 589824 + (size_t)h * 48 + w;
  float xv[4][4];
  #pragma unroll
  for (int s2 = 0; s2 < 4; s2++)
    #pragma unroll
    for (int s1 = 0; s1 < 4; s1++)
      xv[s2][s1] = xb[(size_t)(s2 * 64 + s1 * 16 + c) * 2304];
  float Yv[4][2][2];
  #pragma unroll
  for (int s1 = 0; s1 < 4; s1++) {
    float X0 = xv[0][s1], X1 = xv[1][s1], X2 = xv[2][s1], X3 = xv[3][s1];
    Yv[s1][0][0] = 0.5f * (X0 - X1 - X2 + X3);
    Yv[s1][0][1] = 0.5f * (X0 + X1 - X2 - X3);
    Yv[s1][1][0] = 0.5f * (X0 - X1 + X2 - X3);
    Yv[s1][1][1] = 0.5f * (X0 + X1 + X2 + X3);
  }
  float* zb = Z + (size_t)b * 2359296 + (size_t)(g * 16 + c) * 36864;
  #pragma unroll
  for (int p = 0; p < 2; p++)
    #pragma unroll
    for (int i = 0; i < 2; i++) {
      float Y0q0 = Yv[0][p][0], Y1q0 = Yv[1][p][0], Y2q0 = Yv[2][p][0], Y3q0 = Yv[3][p][0];
      float Y0q1 = Yv[0][p][1], Y1q1 = Yv[1][p][1], Y2q1 = Yv[2][p][1], Y3q1 = Yv[3][p][1];
      float si = (i == 0) ? -1.f : 1.f;
      float zq0j0 = 0.5f * (Y0q0 - Y1q0 + si * Y2q0 - si * Y3q0);
      float zq0j1 = 0.5f * (Y0q0 + Y1q0 + si * Y2q0 + si * Y3q0);
      float zq1j0 = 0.5f * (Y0q1 - Y1q1 + si * Y2q1 - si * Y3q1);
      float zq1j1 = 0.5f * (Y0q1 + Y1q1 + si * Y2q1 + si * Y3q1);
      int off = (4 * h + 2 * p + i) * 192 + 4 * w;
      float4 cur = *(float4*)&zb[off];
      cur.x += zq0j0; cur.y += zq0j1; cur.z += zq1j0; cur.w += zq1j1;
      *(float4*)&zb[off] = cur;
    }
}

// ---------------- qkv einsum v3: 16 outputs x 3 pixels per thread ----------------
__global__ __launch_bounds__(256, 4) void qkv_kernel(const float* __restrict__ in, const float* __restrict__ w,
                           float* __restrict__ out, int C, int HW, long long ibStride, int ig0) {
  int PT = HW / 768;
  int OT3 = (3 * C) >> 4;
  int blk = blockIdx.x;
  int pt = blk % PT; int t = blk / PT; int ot = t % OT3; int b = t / OT3;
  int p = pt * 768 + threadIdx.x;                      // p, p+256, p+512
  const float* ip = in + (size_t)b * ibStride + (size_t)ig0 * HW + p;
  int o0 = ot * 16;
  float acc[3][16];
  #pragma unroll
  for (int u = 0; u < 3; u++)
    #pragma unroll
    for (int i = 0; i < 16; i++) acc[u][i] = 0.f;
  for (int c = 0; c < C; c += 4) {
    float v[3][4];
    #pragma unroll
    for (int j = 0; j < 4; j++) {
      const float* cp = ip + (size_t)(c + j) * HW;
      v[0][j] = cp[0]; v[1][j] = cp[256]; v[2][j] = cp[512];
    }
    #pragma unroll
    for (int i = 0; i < 16; i++) {
      const float4 wv = *(const float4*)(w + (size_t)(o0 + i) * C + c);   // uniform -> s_load_dwordx4
      #pragma unroll
      for (int u = 0; u < 3; u++)
        acc[u][i] += v[u][0] * wv.x + v[u][1] * wv.y + v[u][2] * wv.z + v[u][3] * wv.w;
    }
  }
  float* op = out + ((size_t)b * 3 * C + o0) * HW + p;
  #pragma unroll
  for (int i = 0; i < 16; i++) {
    float* r = op + (size_t)i * HW;
    r[0] = acc[0][i]; r[256] = acc[1][i]; r[512] = acc[2][i];
  }
}

// ---------------- halo attention v2: lane<->query row, wave<->j/d slice ----------------
template <int D>
__global__ __launch_bounds__(256) void attn_kernel(
    const float* __restrict__ qkv, const float* __restrict__ rh, const float* __restrict__ rw,
    float* __restrict__ out, int nh, int nw, int H, int W, long long obStride, int og0, int addFlag) {
  constexpr int DC = (D < 32) ? D : 32;
  constexpr int NCH = D / DC;
  constexpr int HALF = D / 2;
  constexpr int SKS = DC + 4;
  constexpr int CPW = DC / 4;
  __shared__ __align__(16) float sK[100 * SKS];
  __shared__ float sS[64 * 101];
  int blk = blockIdx.x; int nb = nh * nw;
  int b = blk / nb; int r = blk % nb; int by = r / nw; int bx = r % nw;
  size_t HWs = (size_t)H * W;
  const float* qb = qkv + (size_t)b * 3 * D * HWs;
  float qs = rsqrtf((float)D);
  int tid = threadIdx.x;
  int w = tid >> 6, lane = tid & 63;
  int qy = by * 8 + (lane >> 3), qx = bx * 8 + (lane & 7);
  const float* qpix = qb + (size_t)qy * W + qx;
  float acc[25];
  #pragma unroll
  for (int jj = 0; jj < 25; jj++) acc[jj] = 0.f;
  for (int ch = 0; ch < NCH; ch++) {
    int dc0 = ch * DC;
    if (ch) __syncthreads();
    for (int idx = tid; idx < 100 * DC; idx += TPB) {
      int j = idx % 100, c = idx / 100;
      int pr = j / 10, pc = j % 10;
      int hy = by * 8 - 1 + pr, hx = bx * 8 - 1 + pc;
      float v = 0.f;
      if (hy >= 0 && hy < H && hx >= 0 && hx < W)
        v = qb[(size_t)(D + dc0 + c) * HWs + (size_t)hy * W + hx];
      int cg = dc0 + c;
      v += (cg < HALF) ? rh[pr * HALF + cg] : rw[pc * HALF + (cg - HALF)];
      sK[j * SKS + c] = v;
    }
    __syncthreads();
    float qr[DC];
    #pragma unroll
    for (int c = 0; c < DC; c++) qr[c] = qpix[(size_t)(dc0 + c) * HWs] * qs;
    #pragma unroll
    for (int jj = 0; jj < 25; jj++) {
      int j = w * 25 + jj;
      const float4* k4 = (const float4*)&sK[j * SKS];
      float a = 0.f;
      #pragma unroll
      for (int c4 = 0; c4 < DC / 4; c4++) {
        float4 kv = k4[c4];
        a += qr[4 * c4] * kv.x + qr[4 * c4 + 1] * kv.y + qr[4 * c4 + 2] * kv.z + qr[4 * c4 + 3] * kv.w;
      }
      acc[jj] += a;
    }
  }
  #pragma unroll
  for (int jj = 0; jj < 25; jj++) sS[lane * 101 + w * 25 + jj] = acc[jj];
  __syncthreads();
  if (tid < 64) {
    float mx = -3.4e38f;
    for (int j = 0; j < 100; j++) mx = fmaxf(mx, sS[tid * 101 + j]);
    float s = 0.f;
    for (int j = 0; j < 100; j++) { float e = expf(sS[tid * 101 + j] - mx); sS[tid * 101 + j] = e; s += e; }
    float inv = 1.f / s;
    for (int j = 0; j < 100; j++) sS[tid * 101 + j] *= inv;
  }
  for (int ch = 0; ch < NCH; ch++) {
    int dc0 = ch * DC;
    __syncthreads();
    for (int idx = tid; idx < 100 * DC; idx += TPB) {
      int j = idx % 100, c = idx / 100;
      int pr = j / 10, pc = j % 10;
      int hy = by * 8 - 1 + pr, hx = bx * 8 - 1 + pc;
      float v = 0.f;
      if (hy >= 0 && hy < H && hx >= 0 && hx < W)
        v = qb[(size_t)(2 * D + dc0 + c) * HWs + (size_t)hy * W + hx];
      sK[j * SKS + c] = v;
    }
    __syncthreads();
    float oacc[CPW];
    #pragma unroll
    for (int cc = 0; cc < CPW; cc++) oacc[cc] = 0.f;
    const float* srow = &sS[lane * 101];
    for (int j = 0; j < 100; j++) {
      float p = srow[j];
      const float4* v4 = (const float4*)&sK[j * SKS + w * CPW];
      #pragma unroll
      for (int c4 = 0; c4 < CPW / 4; c4++) {
        float4 vv = v4[c4];
        oacc[4 * c4]     += p * vv.x;
        oacc[4 * c4 + 1] += p * vv.y;
        oacc[4 * c4 + 2] += p * vv.z;
        oacc[4 * c4 + 3] += p * vv.w;
      }
    }
    size_t o = (size_t)b * obStride + (size_t)(og0 + dc0 + w * CPW) * HWs + (size_t)qy * W + qx;
    #pragma unroll
    for (int cc = 0; cc < CPW; cc++) {
      if (addFlag) out[o + (size_t)cc * HWs] += oacc[cc];
      else         out[o + (size_t)cc * HWs]  = oacc[cc];
    }
  }
}

// ---------------- ff conv 3x3 zero-pad 64->64 + bias + residual (in-place Y) ----------------
// v4: qkv-style register-tiled direct conv. No LDS, no barriers. One thread = 1 pixel x 16 oc.
// 9-tap neighborhood loaded per-ic from global (coalesced, L1 row reuse); zero-pad via
// precomputed clamp+mask; weights via wave-uniform s_loads. FMA:VMEM = 144:9.
__global__ __launch_bounds__(256) void ffconv_kernel(const float* __restrict__ Z,
    const float* __restrict__ w, const float* __restrict__ bias, float* __restrict__ Y) {
  int blk = blockIdx.x;                               // b*576 + ocg*144 + tile
  int tile = blk % 144; int t2 = blk / 144; int ocg = t2 & 3; int b = t2 >> 2;
  int ty = (tile / 12) * 16, tx = (tile % 12) * 16;
  int tid = threadIdx.x;
  int px = tid & 15, py = tid >> 4;
  int h = ty + py, wc = tx + px;
  const float* zb = Z + (size_t)b * 2359296;
  int off[9]; float msk[9];
  #pragma unroll
  for (int kh = 0; kh < 3; kh++)
    #pragma unroll
    for (int kw = 0; kw < 3; kw++) {
      int hh = h + kh - 1, ww = wc + kw - 1;
      bool v = (hh >= 0 && hh < 192 && ww >= 0 && ww < 192);
      int hcl = min(max(hh, 0), 191), wcl = min(max(ww, 0), 191);
      off[kh * 3 + kw] = hcl * 192 + wcl;
      msk[kh * 3 + kw] = v ? 1.f : 0.f;
    }
  int oc0 = ocg * 16;
  float acc[16];
  #pragma unroll
  for (int oc = 0; oc < 16; oc++) acc[oc] = bias[oc0 + oc];   // uniform -> s_load
  for (int ic = 0; ic < 64; ic++) {
    const float* zc = zb + (size_t)ic * 36864;
    float xv[9];
    #pragma unroll
    for (int t = 0; t < 9; t++) xv[t] = zc[off[t]] * msk[t];
    const float* wp = w + ((size_t)oc0 * 64 + ic) * 9;        // uniform base
    #pragma unroll
    for (int oc = 0; oc < 16; oc++) {
      float a = acc[oc];
      const float* wr = wp + (size_t)oc * 576;                // uniform -> s_load
      #pragma unroll
      for (int k = 0; k < 9; k++) a += xv[k] * wr[k];
      acc[oc] = a;
    }
  }
  size_t base = (size_t)b * 2359296 + (size_t)oc0 * 36864 + (size_t)h * 192 + wc;
  #pragma unroll
  for (int oc = 0; oc < 16; oc++) {
    size_t o = base + (size_t)oc * 36864;
    Y[o] = acc[oc] + Y[o];
  }
}

// ---------------- t1: (Y+R) conv1x1(64->256) + pixel_shuffle(2) + gelu -> U1 ----------------
__global__ __launch_bounds__(256, 4) void t1_kernel(const float* __restrict__ Y, const float* __restrict__ R,
    const float* __restrict__ w, const float* __restrict__ bias, float* __restrict__ U1) {
  int blk = blockIdx.x; int b = blk / 144; int p0 = (blk % 144) * 256;
  int tid = threadIdx.x;
  int p = p0 + tid;
  float yv[64];
  const float* yp = Y + (size_t)b * 2359296 + p;
  const float* rp = R + (size_t)b * 2359296 + p;
  #pragma unroll
  for (int c = 0; c < 64; c++) yv[c] = yp[(size_t)c * 36864] + rp[(size_t)c * 36864];
  int h = p / 192, wc = p % 192;
  float* ub = U1 + (size_t)b * 9437184 + (size_t)(2 * h) * 384 + 2 * wc;
  for (int c2 = 0; c2 < 64; c2++) {
    float a0 = bias[c2 * 4 + 0], a1 = bias[c2 * 4 + 1], a2 = bias[c2 * 4 + 2], a3 = bias[c2 * 4 + 3];
    const float* w0 = w + (size_t)(c2 * 4) * 64;
    const float* w1 = w0 + 64; const float* w2p = w0 + 128; const float* w3p = w0 + 192;
    #pragma unroll
    for (int c = 0; c < 64; c++) {
      float y = yv[c];
      a0 += y * w0[c]; a1 += y * w1[c]; a2 += y * w2p[c]; a3 += y * w3p[c];
    }
    float* up = ub + (size_t)c2 * 147456;
    up[0] = gelu_f(a0); up[1] = gelu_f(a1); up[384] = gelu_f(a2); up[385] = gelu_f(a3);
  }
}

// ---------------- fused tail: t2 conv1x1+ps+gelu -> t3 conv3x3(reflect) -> clip ----------------
__global__ __launch_bounds__(256, 4) void tail_kernel(const float* __restrict__ U1,
    const float* __restrict__ w2, const float* __restrict__ b2,
    const float* __restrict__ w3, float* __restrict__ out) {
  __shared__ float2 sU2p[4][1024];                    // plane q: ic pair (2q,2q+1), pix 32x32
  int blk = blockIdx.x;
  int b = blk / 784; int tile = blk % 784;
  int tr = tile / 28, tc = tile % 28;
  int r0 = tr * 28, c0 = tc * 28;
  int s0 = (r0 >> 1) - 1, t0 = (c0 >> 1) - 1;
  int tid = threadIdx.x;
  int ls = tid >> 4, lt = tid & 15;
  int gs = min(max(s0 + ls, 0), 383);
  int gt = min(max(t0 + lt, 0), 383);
  const float* ub = U1 + (size_t)b * 9437184 + (size_t)gs * 384 + gt;
  int orow[4], ocol[4]; bool val[4];
  #pragma unroll
  for (int k = 0; k < 4; k++) {
    int p = tid + k * 256;
    int y = p / 28, x = p % 28;
    orow[k] = r0 + y; ocol[k] = c0 + x;
    val[k] = (p < 784) && (orow[k] < 768) && (ocol[k] < 768);
  }
  float acc0[4], acc1[4], acc2[4];
  #pragma unroll
  for (int k = 0; k < 4; k++) { acc0[k] = 0.f; acc1[k] = 0.f; acc2[k] = 0.f; }
  int urow = 2 * ls, ucol = 2 * lt;
  int mypix[4];
  #pragma unroll
  for (int par = 0; par < 4; par++) mypix[par] = (urow + (par >> 1)) * 32 + (ucol + (par & 1));
  for (int ch = 0; ch < 8; ch++) {
    if (ch) __syncthreads();
    // ---- t2 half 0: ic 0..31, store raw partials ----
    {
      float u1v[32];
      #pragma unroll
      for (int c = 0; c < 32; c++) u1v[c] = ub[(size_t)c * 147456];
      #pragma unroll
      for (int rg = 0; rg < 4; rg++) {
        float av[8];
        #pragma unroll
        for (int r = 0; r < 8; r++) av[r] = b2[ch * 32 + rg * 8 + r];
        #pragma unroll
        for (int c4 = 0; c4 < 8; c4++) {
          float ux = u1v[4 * c4], uy = u1v[4 * c4 + 1], uz = u1v[4 * c4 + 2], uw = u1v[4 * c4 + 3];
          #pragma unroll
          for (int r = 0; r < 8; r++) {
            const float4 wv = *(const float4*)(w2 + (size_t)(ch * 32 + rg * 8 + r) * 64 + c4 * 4);
            av[r] += ux * wv.x + uy * wv.y + uz * wv.z + uw * wv.w;
          }
        }
        #pragma unroll
        for (int par = 0; par < 4; par++)
          sU2p[rg][mypix[par]] = make_float2(av[par], av[4 + par]);   // raw partial
      }
    }
    // ---- t2 half 1: ic 32..63, accumulate + gelu ----
    {
      float u1v[32];
      #pragma unroll
      for (int c = 0; c < 32; c++) u1v[c] = ub[(size_t)(32 + c) * 147456];
      #pragma unroll
      for (int rg = 0; rg < 4; rg++) {
        float av[8];
        #pragma unroll
        for (int par = 0; par < 4; par++) {
          float2 pv = sU2p[rg][mypix[par]];            // own slot, same thread
          av[par] = pv.x; av[4 + par] = pv.y;
        }
        #pragma unroll
        for (int c4 = 0; c4 < 8; c4++) {
          float ux = u1v[4 * c4], uy = u1v[4 * c4 + 1], uz = u1v[4 * c4 + 2], uw = u1v[4 * c4 + 3];
          #pragma unroll
          for (int r = 0; r < 8; r++) {
            const float4 wv = *(const float4*)(w2 + (size_t)(ch * 32 + rg * 8 + r) * 64 + 32 + c4 * 4);
            av[r] += ux * wv.x + uy * wv.y + uz * wv.z + uw * wv.w;
          }
        }
        #pragma unroll
        for (int par = 0; par < 4; par++)
          sU2p[rg][mypix[par]] = make_float2(gelu_f(av[par]), gelu_f(av[4 + par]));
      }
    }
    __syncthreads();
    // ---- t3 partial accumulation ----
    #pragma unroll
    for (int k = 0; k < 4; k++) {
      if (!val[k]) continue;
      float s0a = acc0[k], s1a = acc1[k], s2a = acc2[k];
      #pragma unroll
      for (int kh = 0; kh < 3; kh++) {
        int pp = orow[k] - 1 + kh; int mp = pp < 0 ? -pp : (pp > 767 ? 1534 - pp : pp);
        int lr = mp - r0 + 2;
        #pragma unroll
        for (int kw = 0; kw < 3; kw++) {
          int qq = ocol[k] - 1 + kw; int mq = qq < 0 ? -qq : (qq > 767 ? 1534 - qq : qq);
          int lc = mq - c0 + 2;
          int pix = lr * 32 + lc;
          float2 u01 = sU2p[0][pix], u23 = sU2p[1][pix], u45 = sU2p[2][pix], u67 = sU2p[3][pix];
          const float* w3p = w3 + (size_t)(ch * 8) * 9 + kh * 3 + kw;   // + oc*576 + g*9
          s0a += u01.x * w3p[0]    + u01.y * w3p[9]    + u23.x * w3p[18]   + u23.y * w3p[27]
               + u45.x * w3p[36]   + u45.y * w3p[45]   + u67.x * w3p[54]   + u67.y * w3p[63];
          s1a += u01.x * w3p[576]  + u01.y * w3p[585]  + u23.x * w3p[594]  + u23.y * w3p[603]
               + u45.x * w3p[612]  + u45.y * w3p[621]  + u67.x * w3p[630]  + u67.y * w3p[639];
          s2a += u01.x * w3p[1152] + u01.y * w3p[1161] + u23.x * w3p[1170] + u23.y * w3p[1179]
               + u45.x * w3p[1188] + u45.y * w3p[1197] + u67.x * w3p[1206] + u67.y * w3p[1215];
        }
      }
      acc0[k] = s0a; acc1[k] = s1a; acc2[k] = s2a;
    }
  }
  #pragma unroll
  for (int k = 0; k < 4; k++) {
    if (!val[k]) continue;
    size_t o = ((size_t)b * 3 * 768 + orow[k]) * 768 + ocol[k];
    out[o] = fminf(fmaxf(acc0[k], 0.f), 1.f);
    out[o + 589824] = fminf(fmaxf(acc1[k], 0.f), 1.f);
    out[o + 1179648] = fminf(fmaxf(acc2[k], 0.f), 1.f);
  }
}

extern "C" void kernel_launch(void* const* d_in, const int* in_sizes, int n_in,
                              void* d_out, int out_size, void* d_ws, size_t ws_size,
                              hipStream_t stream) {
  const float* x      = (const float*)d_in[0];
  const float* head_w = (const float*)d_in[1];
  const float* head_b = (const float*)d_in[2];
  const float* a_qkv[4] = {(const float*)d_in[3], (const float*)d_in[6], (const float*)d_in[9],  (const float*)d_in[12]};
  const float* a_rh[4]  = {(const float*)d_in[4], (const float*)d_in[7], (const float*)d_in[10], (const float*)d_in[13]};
  const float* a_rw[4]  = {(const float*)d_in[5], (const float*)d_in[8], (const float*)d_in[11], (const float*)d_in[14]};
  const float* ff_w = (const float*)d_in[15];
  const float* ff_b = (const float*)d_in[16];
  const float* t1_w = (const float*)d_in[17];
  const float* t1_b = (const float*)d_in[18];
  const float* t2_w = (const float*)d_in[19];
  const float* t2_b = (const float*)d_in[20];
  const float* t3_w = (const float*)d_in[21];
  float* outp = (float*)d_out;
  float* wsf = (float*)d_ws;

  const size_t F = 9437184;                 // 4*64*192*192
  float* R   = wsf;
  float* Y   = wsf + F;
  float* Z   = wsf + 2 * F;
  float* QKV = wsf + 3 * F;                 // 7,077,888 floats
  float* AO  = QKV + 7077888;               // 2,359,296
  float* D1  = AO + 2359296;                // 2,359,296
  float* D2  = D1 + 2359296;                // 2,359,296
  float* U1  = Z;                           // tail reuses CFTM scratch

  head_conv_kernel<<<36864, TPB, 0, stream>>>(x, head_w, head_b, R, Y);

  for (int bi = 0; bi < 4; bi++) {
    instnorm_kernel<<<256, TPB, 0, stream>>>(Y, Z);
    // branch 1 (d=16, 192x192)
    qkv_kernel<<<576, TPB, 0, stream>>>(Z, a_qkv[0] + bi * 768, QKV, 16, 36864, 2359296LL, 0);
    attn_kernel<16><<<2304, TPB, 0, stream>>>(QKV, a_rh[0] + bi * 80, a_rw[0] + bi * 80, Z,
                                              24, 24, 192, 192, 2359296LL, 0, 1);
    // branch 2 (d=64, 96x96)
    mixdwt1_kernel<<<2304, TPB, 0, stream>>>(Z, D1, 1);
    qkv_kernel<<<576, TPB, 0, stream>>>(D1, a_qkv[1] + bi * 12288, QKV, 64, 9216, 589824LL, 0);
    attn_kernel<64><<<576, TPB, 0, stream>>>(QKV, a_rh[1] + bi * 320, a_rw[1] + bi * 320, AO,
                                             12, 12, 96, 96, 589824LL, 0, 0);
    iwt_kernel<<<2304, TPB, 0, stream>>>(AO, Z, 16, 96, 96, 2359296LL, 16, 1);
    // branch 3 (d=256, 48x48)
    mixdwt2_kernel<<<576, TPB, 0, stream>>>(Z, D2, 2);
    qkv_kernel<<<576, TPB, 0, stream>>>(D2, a_qkv[2] + bi * 196608, QKV, 256, 2304, 589824LL, 0);
    attn_kernel<256><<<144, TPB, 0, stream>>>(QKV, a_rh[2] + bi * 1280, a_rw[2] + bi * 1280, AO,
                                              6, 6, 48, 48, 589824LL, 0, 0);
    iwt2add_kernel<<<576, TPB, 0, stream>>>(AO, Z, 2);
    // branch 4 (d=256, 48x48)
    mixdwt2_kernel<<<576, TPB, 0, stream>>>(Z, D2, 3);
    qkv_kernel<<<576, TPB, 0, stream>>>(D2, a_qkv[3] + bi * 196608, QKV, 256, 2304, 589824LL, 0);
    attn_kernel<256><<<144, TPB, 0, stream>>>(QKV, a_rh[3] + bi * 1280, a_rw[3] + bi * 1280, AO,
                                              6, 6, 48, 48, 589824LL, 0, 0);
    iwt2add_kernel<<<576, TPB, 0, stream>>>(AO, Z, 3);
    // ff conv + residual
    ffconv_kernel<<<2304, TPB, 0, stream>>>(Z, ff_w + bi * 36864, ff_b + bi * 64, Y);
  }

  t1_kernel<<<576, TPB, 0, stream>>>(Y, R, t1_w, t1_b, U1);
  tail_kernel<<<3136, TPB, 0, stream>>>(U1, t2_w, t2_b, t3_w, outp);
}